// Round 5
// baseline (511.595 us; speedup 1.0000x reference)
//
#include <hip/hip_runtime.h>
#include <stdint.h>

typedef _Float16 half8 __attribute__((ext_vector_type(8)));
typedef float f32x4 __attribute__((ext_vector_type(4)));

typedef const __attribute__((address_space(1))) void* gptr_t;
typedef __attribute__((address_space(3))) void* lptr_t;
static __device__ __forceinline__ void gll16(const void* g, void* l) {
  __builtin_amdgcn_global_load_lds((gptr_t)(unsigned long long)g,
                                   (lptr_t)(unsigned int)(unsigned long long)l,
                                   16, 0, 0);
}

// =================== k_prep: one launch for all setup ===================
// blocks 0..143 : P = M@W2 -> Btl f16 (l = b/36, col-tile = b%36; M recomputed per block)
// blocks 144..147: root_w[l] -> Btl rows 960..1151
// block 148      : Cheb chain -> Tx[5][4096]
// block 149      : CSR by dst + sorted edge attrs
__global__ __launch_bounds__(256)
void k_prep(const float* __restrict__ x, const int* __restrict__ ei,
            const float* __restrict__ eattr,
            const float* __restrict__ eenc_w, const float* __restrict__ eenc_b,
            const float* __restrict__ nn1_w, const float* __restrict__ nn1_b,
            const float* __restrict__ nn2_w, const float* __restrict__ nn2_b,
            const float* __restrict__ root_w,
            float* __restrict__ Tx, _Float16* __restrict__ Btl,
            int* __restrict__ row_ptr, int* __restrict__ src_sorted,
            float4* __restrict__ attr_sorted) {
  __shared__ float smf[15360];  // 60 KB, aliased per role
  const int b = blockIdx.x, t = threadIdx.x;

  if (b < 144) {
    const int l = b / 36, tile = b - l * 36;
    const float* nn1l = nn1_w + (size_t)l * 36864;
    float* Ms = smf;  // [5][192]
    if (t < 192) {
      float a0 = 0.f, a1 = 0.f, a2 = 0.f, a3 = 0.f, a4 = 0.f;
      for (int kk = 0; kk < 192; ++kk) {
        float nv = nn1l[(size_t)kk * 192 + t];
        a0 += eenc_w[kk] * nv;
        a1 += eenc_w[192 + kk] * nv;
        a2 += eenc_w[384 + kk] * nv;
        a3 += eenc_w[576 + kk] * nv;
        a4 += eenc_b[kk] * nv;
      }
      Ms[t] = a0; Ms[192 + t] = a1; Ms[384 + t] = a2; Ms[576 + t] = a3;
      Ms[768 + t] = a4 + nn1_b[l * 192 + t];
    }
    __syncthreads();
    const int col = tile * 1024 + t * 4;
    const float* W2l = nn2_w + (size_t)l * 7077888 + col;
    f32x4 ac0 = {}, ac1 = {}, ac2 = {}, ac3 = {}, ac4 = {};
#pragma unroll 8
    for (int k = 0; k < 192; ++k) {
      f32x4 wv = *(const f32x4*)(W2l + (size_t)k * 36864);
      ac0 += wv * Ms[k];
      ac1 += wv * Ms[192 + k];
      ac2 += wv * Ms[384 + k];
      ac3 += wv * Ms[576 + k];
      ac4 += wv * Ms[768 + k];
    }
    f32x4 b4 = *(const f32x4*)(nn2_b + (size_t)l * 36864 + col);
    ac4 += b4;
    _Float16* Bo = Btl + (size_t)l * 221184;
    f32x4 accs[5] = {ac0, ac1, ac2, ac3, ac4};
#pragma unroll
    for (int c = 0; c < 5; ++c)
#pragma unroll
      for (int q = 0; q < 4; ++q) {
        int f = col + q;
        int i = f / 192, o = f - i * 192;
        int k = c * 192 + i;
        Bo[((size_t)(k >> 3) * 192 + o) * 8 + (k & 7)] = (_Float16)accs[c][q];
      }
  } else if (b < 148) {
    const int l = b - 144;
    _Float16* Bo = Btl + (size_t)l * 221184;
    const float* rw = root_w + (size_t)l * 36864;
#pragma unroll 4
    for (int it = 0; it < 144; ++it) {
      int e2 = it * 256 + t;
      int j = e2 / 192, o = e2 - j * 192;
      int k = 960 + j;
      Bo[((size_t)(k >> 3) * 192 + o) * 8 + (k & 7)] = (_Float16)rw[e2];
    }
  } else if (b == 148) {
    float* deg = smf;            // 1024
    float* wn2 = smf + 1024;     // 2048
    float* T0 = smf + 3072;      // 4096
    float* T1 = smf + 7168;      // 4096
    float* yv = smf + 11264;     // 4096
    for (int i = t; i < 1024; i += 256) deg[i] = 0.f;
    __syncthreads();
    for (int e = t; e < 2048; e += 256) atomicAdd(&deg[ei[e]], 1.f);
    __syncthreads();
    for (int e = t; e < 2048; e += 256) {
      int s = ei[e], d = ei[2048 + e];
      float ds = deg[s], dd = deg[d];
      float a = ds > 0.f ? 1.f / sqrtf(fmaxf(ds, 1.f)) : 0.f;
      float bb = dd > 0.f ? 1.f / sqrtf(fmaxf(dd, 1.f)) : 0.f;
      wn2[e] = -a * bb;
    }
    for (int i = t; i < 1024; i += 256) {
      float4 xv = ((const float4*)x)[i];
      ((float4*)T0)[i] = xv;
      ((float4*)Tx)[i] = xv;
    }
    __syncthreads();
    float* cur = T0; float* nxt = T1;
    for (int rec = 0; rec < 4; ++rec) {
      for (int i = t; i < 1024; i += 256) ((float4*)yv)[i] = make_float4(0.f, 0.f, 0.f, 0.f);
      __syncthreads();
      for (int e = t; e < 2048; e += 256) {
        int s = ei[e], d = ei[2048 + e];
        float wv = wn2[e];
#pragma unroll
        for (int c = 0; c < 4; ++c) atomicAdd(&yv[d * 4 + c], wv * cur[s * 4 + c]);
      }
      __syncthreads();
      float a = (rec == 0) ? 1.f : 2.f;
      for (int i = t; i < 1024; i += 256) {
        float4 y4 = ((float4*)yv)[i];
        float4 p4 = ((float4*)nxt)[i];
        float4 n4;
        n4.x = a * y4.x - (rec ? p4.x : 0.f);
        n4.y = a * y4.y - (rec ? p4.y : 0.f);
        n4.z = a * y4.z - (rec ? p4.z : 0.f);
        n4.w = a * y4.w - (rec ? p4.w : 0.f);
        ((float4*)nxt)[i] = n4;
        ((float4*)(Tx + (rec + 1) * 4096))[i] = n4;
      }
      __syncthreads();
      float* tmp = cur; cur = nxt; nxt = tmp;
    }
  } else {
    // CSR build by dst
    int* cnt = (int*)smf;       // 1024
    int* sa = cnt + 1024;
    int* sb = sa + 1024;
    int* cur = sb + 1024;
    for (int i = t; i < 1024; i += 256) cnt[i] = 0;
    __syncthreads();
    for (int e = t; e < 2048; e += 256) atomicAdd(&cnt[ei[2048 + e]], 1);
    __syncthreads();
    for (int i = t; i < 1024; i += 256) sa[i] = cnt[i];
    __syncthreads();
    for (int off = 1; off < 1024; off <<= 1) {
      for (int i = t; i < 1024; i += 256) sb[i] = sa[i] + ((i >= off) ? sa[i - off] : 0);
      __syncthreads();
      int* tmp = sa; sa = sb; sb = tmp;
      // note: sa now holds the updated scan; loop barrier pattern is uniform
      __syncthreads();
    }
    for (int i = t; i < 1024; i += 256) {
      int excl = sa[i] - cnt[i];
      cur[i] = excl;
      row_ptr[i] = excl;
    }
    if (t == 0) row_ptr[1024] = 2048;
    __syncthreads();
    for (int e = t; e < 2048; e += 256) {
      int d = ei[2048 + e], s = ei[e];
      int pos = atomicAdd(&cur[d], 1);
      src_sorted[pos] = s;
      attr_sorted[pos] = ((const float4*)eattr)[e];
    }
  }
}

// =================== k_layer: one launch per layer ===================
// 8 blocks x 512 thr. Block b owns rows [b*128, b*128+128).
// Phase 1: gather-build X=[g0..g4|z] f16 chunk-major -> private global scratch Xp.
// Phase 2: stream Xp + Btl, MFMA GEMM K=1152.
// Phase 3: epilogue conv_b + residual + LN + relu -> h, zdst. l==3: fused head.
__global__ __launch_bounds__(512, 1)
void k_layer(int l, const float* __restrict__ Tx, const float* __restrict__ cheb_w,
             const float* __restrict__ cheb_b, const int* __restrict__ row_ptr,
             const int* __restrict__ src_sorted, const float4* __restrict__ attr_sorted,
             const float* __restrict__ zsrc, float* __restrict__ zdst,
             float* __restrict__ h, _Float16* __restrict__ Xp,
             const _Float16* __restrict__ Btl,
             const float* __restrict__ conv_b, const float* __restrict__ ln_g,
             const float* __restrict__ ln_b, const float* __restrict__ out_w,
             const float* __restrict__ out_b, float* __restrict__ outp) {
  extern __shared__ _Float16 sm[];
  _Float16* As = sm;                 // 2 x 8 x 128 x 8 = 16384 halfs
  _Float16* Bs = sm + 16384;         // 2 x 8 x 192 x 8 = 24576 halfs
  float* cwl = (float*)(Bs + 24576); // 3840
  float* cbl = cwl + 3840;           // 192
  float* s1 = cbl + 192;             // 512
  float* s2 = s1 + 512;              // 512

  const int tid = threadIdx.x;
  const int w = tid >> 6, lane = tid & 63;
  const int l15 = lane & 15, q4 = lane >> 4;
  const int wm = w >> 2, wn = w & 3;
  const int b = blockIdx.x;
  const int R0 = b * 128;
  const int l0f = (l == 0);
  _Float16* Xpb = Xp + (size_t)b * 147456;
  const _Float16* Btll = Btl + (size_t)l * 221184;

  if (l0f) {
    for (int i = tid; i < 3840; i += 512) cwl[i] = cheb_w[i];
    if (tid < 192) cbl[tid] = cheb_b[tid];
    __syncthreads();
  }

  // ---- Phase 1: gather + X build (wave w owns rows w*16 .. w*16+15) ----
  for (int rr = 0; rr < 16; ++rr) {
    const int r = w * 16 + rr;
    const int R = R0 + r;
    float g[5][3];
#pragma unroll
    for (int c = 0; c < 5; ++c)
#pragma unroll
      for (int q = 0; q < 3; ++q) g[c][q] = 0.f;
    const int e0 = row_ptr[R], e1 = row_ptr[R + 1];
    for (int e = e0; e < e1; ++e) {
      const int s = src_sorted[e];
      const float4 u = attr_sorted[e];
      float zq[3];
      if (l0f) {
        float txv[20];
#pragma unroll
        for (int j = 0; j < 20; ++j) txv[j] = Tx[(j >> 2) * 4096 + s * 4 + (j & 3)];
#pragma unroll
        for (int q = 0; q < 3; ++q) {
          int col = lane + 64 * q;
          float v = cbl[col];
#pragma unroll
          for (int j = 0; j < 20; ++j) v += txv[j] * cwl[j * 192 + col];
          zq[q] = v;
        }
      } else {
#pragma unroll
        for (int q = 0; q < 3; ++q) zq[q] = zsrc[(size_t)s * 192 + lane + 64 * q];
      }
#pragma unroll
      for (int q = 0; q < 3; ++q) {
        g[0][q] += u.x * zq[q];
        g[1][q] += u.y * zq[q];
        g[2][q] += u.z * zq[q];
        g[3][q] += u.w * zq[q];
        g[4][q] += zq[q];
      }
    }
    // own-row z (X z-part)
    float zo[3];
    if (l0f) {
      float txv[20];
#pragma unroll
      for (int j = 0; j < 20; ++j) txv[j] = Tx[(j >> 2) * 4096 + R * 4 + (j & 3)];
#pragma unroll
      for (int q = 0; q < 3; ++q) {
        int col = lane + 64 * q;
        float v = cbl[col];
#pragma unroll
        for (int j = 0; j < 20; ++j) v += txv[j] * cwl[j * 192 + col];
        zo[q] = v;
      }
    } else {
#pragma unroll
      for (int q = 0; q < 3; ++q) zo[q] = zsrc[(size_t)R * 192 + lane + 64 * q];
    }
#pragma unroll
    for (int c = 0; c < 5; ++c)
#pragma unroll
      for (int q = 0; q < 3; ++q) {
        int i = lane + 64 * q;
        int k = c * 192 + i;
        Xpb[((size_t)(k >> 3) * 128 + r) * 8 + (i & 7)] = (_Float16)g[c][q];
      }
#pragma unroll
    for (int q = 0; q < 3; ++q) {
      int i = lane + 64 * q;
      int k = 960 + i;
      Xpb[((size_t)(k >> 3) * 128 + r) * 8 + (i & 7)] = (_Float16)zo[q];
    }
  }
  __syncthreads();  // drains vmcnt: Xp visible in L2 for read-back

  // ---- Phase 2: GEMM, 18 slabs of 8 chunks, double-buffered ----
  f32x4 acc[4][3] = {};
  // stage slab 0 into buf 0
  {
#pragma unroll
    for (int it = 0; it < 2; ++it) {
      int u = it * 512 + tid;
      int ck = u >> 7, r = u & 127;
      gll16(Xpb + ((size_t)ck * 128 + r) * 8, (char*)As + (ck * 1024 + r * 8) * 2);
    }
#pragma unroll
    for (int it = 0; it < 3; ++it) {
      int u = it * 512 + tid;
      int ck = u / 192, o = u - ck * 192;
      gll16(Btll + ((size_t)ck * 192 + o) * 8, (char*)Bs + (ck * 1536 + o * 8) * 2);
    }
  }
  __syncthreads();
  int buf = 0;
  for (int s = 0; s < 18; ++s) {
    if (s < 17) {
      const int sb2 = (s + 1) * 8;
      const int bo = (buf ^ 1);
#pragma unroll
      for (int it = 0; it < 2; ++it) {
        int u = it * 512 + tid;
        int ck = u >> 7, r = u & 127;
        gll16(Xpb + ((size_t)(sb2 + ck) * 128 + r) * 8,
              (char*)As + (bo * 8192 + ck * 1024 + r * 8) * 2);
      }
#pragma unroll
      for (int it = 0; it < 3; ++it) {
        int u = it * 512 + tid;
        int ck = u / 192, o = u - ck * 192;
        gll16(Btll + ((size_t)(sb2 + ck) * 192 + o) * 8,
              (char*)Bs + (bo * 12288 + ck * 1536 + o * 8) * 2);
      }
    }
#pragma unroll
    for (int h2 = 0; h2 < 2; ++h2) {
      half8 av[4];
#pragma unroll
      for (int mt = 0; mt < 4; ++mt)
        av[mt] = *(const half8*)(As + buf * 8192 + (h2 * 4 + q4) * 1024 +
                                 (wm * 64 + mt * 16 + l15) * 8);
#pragma unroll
      for (int nt = 0; nt < 3; ++nt) {
        half8 bv = *(const half8*)(Bs + buf * 12288 + (h2 * 4 + q4) * 1536 +
                                   (wn * 48 + nt * 16 + l15) * 8);
#pragma unroll
        for (int mt = 0; mt < 4; ++mt)
          acc[mt][nt] = __builtin_amdgcn_mfma_f32_16x16x32_f16(av[mt], bv, acc[mt][nt], 0, 0, 0);
      }
    }
    __syncthreads();
    buf ^= 1;
  }

  // ---- Phase 3: epilogue ----
  const int gidx = (l == 3) ? 0 : (l + 1);
  const float* lg = ln_g + (size_t)gidx * 192;
  const float* lb = ln_b + (size_t)gidx * 192;
  const float* cbv = conv_b + (size_t)l * 192;
#pragma unroll
  for (int mt = 0; mt < 4; ++mt)
#pragma unroll
    for (int nt = 0; nt < 3; ++nt) {
      int col = wn * 48 + nt * 16 + l15;
      float cb2 = cbv[col];
#pragma unroll
      for (int r = 0; r < 4; ++r) {
        int row = wm * 64 + mt * 16 + q4 * 4 + r;
        int R = R0 + row;
        float v = acc[mt][nt][r] + cb2;
        if (l > 0) v += h[(size_t)R * 192 + col];
        h[(size_t)R * 192 + col] = v;
        acc[mt][nt][r] = v;
      }
    }
  // LN partial sums
#pragma unroll
  for (int mt = 0; mt < 4; ++mt)
#pragma unroll
    for (int r = 0; r < 4; ++r) {
      float p1 = 0.f, p2 = 0.f;
#pragma unroll
      for (int nt = 0; nt < 3; ++nt) {
        float v = acc[mt][nt][r];
        p1 += v; p2 += v * v;
      }
#pragma unroll
      for (int m = 1; m < 16; m <<= 1) {
        p1 += __shfl_xor(p1, m);
        p2 += __shfl_xor(p2, m);
      }
      if (l15 == 0) {
        int row = wm * 64 + mt * 16 + q4 * 4 + r;
        s1[row * 4 + wn] = p1;
        s2[row * 4 + wn] = p2;
      }
    }
  __syncthreads();
#pragma unroll
  for (int mt = 0; mt < 4; ++mt)
#pragma unroll
    for (int r = 0; r < 4; ++r) {
      int row = wm * 64 + mt * 16 + q4 * 4 + r;
      float sum1 = s1[row * 4] + s1[row * 4 + 1] + s1[row * 4 + 2] + s1[row * 4 + 3];
      float sum2 = s2[row * 4] + s2[row * 4 + 1] + s2[row * 4 + 2] + s2[row * 4 + 3];
      float mu = sum1 / 192.f;
      float var = sum2 / 192.f - mu * mu;
      float rs = rsqrtf(var + 1e-5f);
      int R = R0 + row;
#pragma unroll
      for (int nt = 0; nt < 3; ++nt) {
        int col = wn * 48 + nt * 16 + l15;
        float zv = (acc[mt][nt][r] - mu) * rs * lg[col] + lb[col];
        zdst[(size_t)R * 192 + col] = fmaxf(zv, 0.f);
      }
    }
  if (l == 3) {
    __syncthreads();  // zdst writes drained & visible
    if (tid < 256) {
      int rl = tid >> 1, c = tid & 1;
      int R = R0 + rl;
      float a = out_b[c];
      const float* zr = zdst + (size_t)R * 192;
#pragma unroll 8
      for (int j = 0; j < 192; ++j) a += zr[j] * out_w[j * 2 + c];
      outp[(size_t)R * 2 + c] = a;
    }
  }
}

// =================== launch ===================
extern "C" void kernel_launch(void* const* d_in, const int* in_sizes, int n_in,
                              void* d_out, int out_size, void* d_ws, size_t ws_size,
                              hipStream_t stream) {
  const float* x      = (const float*)d_in[0];
  const int*   ei     = (const int*)  d_in[1];
  const float* eattr  = (const float*)d_in[2];
  const float* cheb_w = (const float*)d_in[4];
  const float* cheb_b = (const float*)d_in[5];
  const float* eenc_w = (const float*)d_in[6];
  const float* eenc_b = (const float*)d_in[7];
  const float* nn1_w  = (const float*)d_in[8];
  const float* nn1_b  = (const float*)d_in[9];
  const float* nn2_w  = (const float*)d_in[10];
  const float* nn2_b  = (const float*)d_in[11];
  const float* root_w = (const float*)d_in[12];
  const float* conv_b = (const float*)d_in[13];
  const float* ln_g   = (const float*)d_in[14];
  const float* ln_bb  = (const float*)d_in[15];
  const float* out_w  = (const float*)d_in[16];
  const float* out_b  = (const float*)d_in[17];
  float* outp = (float*)d_out;
  (void)in_sizes; (void)n_in; (void)out_size; (void)ws_size;

  char* p = (char*)d_ws;
  _Float16* Btl  = (_Float16*)p; p += (size_t)4 * 221184 * 2;      // 1.77 MB
  _Float16* Xp   = (_Float16*)p; p += (size_t)8 * 147456 * 2;      // 2.36 MB
  float* Tx      = (float*)p;    p += 5 * 4096 * 4;
  float* h       = (float*)p;    p += 196608 * 4;
  float* zA      = (float*)p;    p += 196608 * 4;
  float* zB      = (float*)p;    p += 196608 * 4;
  float4* attr_s = (float4*)p;   p += 2048 * 16;
  int* row_ptr   = (int*)p;      p += 1056 * 4;
  int* src_s     = (int*)p;      p += 2048 * 4;

  hipFuncSetAttribute(reinterpret_cast<const void*>(&k_layer),
                      hipFuncAttributeMaxDynamicSharedMemorySize, 102400);

  k_prep<<<150, 256, 0, stream>>>(x, ei, eattr, eenc_w, eenc_b, nn1_w, nn1_b,
                                  nn2_w, nn2_b, root_w, Tx, Btl, row_ptr, src_s, attr_s);

  float* zbufs[2] = {zA, zB};
  const float* zsrc = nullptr;  // l=0 uses Tx/cheb path
  for (int l = 0; l < 4; ++l) {
    float* zd = zbufs[l & 1];
    k_layer<<<8, 512, 102400, stream>>>(l, Tx, cheb_w, cheb_b, row_ptr, src_s, attr_s,
                                        zsrc, zd, h, Xp, Btl, conv_b, ln_g, ln_bb,
                                        out_w, out_b, outp);
    zsrc = zd;
  }
}